// Round 11
// baseline (316.435 us; speedup 1.0000x reference)
//
#include <hip/hip_runtime.h>

#define NSZ 128
#define NS3 (NSZ * NSZ * NSZ)
#define NBUCK_D 16           // buckets per dim (bucket = 8^3 cells) -- gather only
#define NBUCK (NBUCK_D * NBUCK_D * NBUCK_D)
#define NCOL 16384           // 128*128 xy columns
#define NZC 8                // z-chunks per column (16 cells each)
#define NCB (NCOL * NZC)     // 131072 column-chunk buckets
#define LROW 129             // padded LDS row stride (complex) for FFT planes
#define LDS_BYTES (NSZ * LROW * sizeof(float2))   // 132096

// ---------- small helpers ----------

__device__ __forceinline__ void inv3x3(const float* __restrict__ c, float* inv) {
    float a00 = c[0], a01 = c[1], a02 = c[2];
    float a10 = c[3], a11 = c[4], a12 = c[5];
    float a20 = c[6], a21 = c[7], a22 = c[8];
    float det = a00 * (a11 * a22 - a12 * a21)
              - a01 * (a10 * a22 - a12 * a20)
              + a02 * (a10 * a21 - a11 * a20);
    float id = 1.0f / det;
    inv[0] = (a11 * a22 - a12 * a21) * id;
    inv[1] = (a02 * a21 - a01 * a22) * id;
    inv[2] = (a01 * a12 - a02 * a11) * id;
    inv[3] = (a12 * a20 - a10 * a22) * id;
    inv[4] = (a00 * a22 - a02 * a20) * id;
    inv[5] = (a02 * a10 - a00 * a12) * id;
    inv[6] = (a10 * a21 - a11 * a20) * id;
    inv[7] = (a01 * a20 - a00 * a21) * id;
    inv[8] = (a00 * a11 - a01 * a10) * id;
}

__device__ __forceinline__ float det3x3(const float* __restrict__ c) {
    return c[0] * (c[4] * c[8] - c[5] * c[7])
         - c[1] * (c[3] * c[8] - c[5] * c[6])
         + c[2] * (c[3] * c[7] - c[4] * c[6]);
}

__device__ __forceinline__ int brev7(int i) { return (int)(__brev((unsigned)i) >> 25); }

__device__ __forceinline__ float2 cadd(float2 a, float2 b) { return make_float2(a.x + b.x, a.y + b.y); }
__device__ __forceinline__ float2 csub(float2 a, float2 b) { return make_float2(a.x - b.x, a.y - b.y); }
__device__ __forceinline__ float2 cmul(float2 a, float2 b) {
    return make_float2(a.x * b.x - a.y * b.y, a.x * b.y + a.y * b.x);
}
__device__ __forceinline__ float2 cmulc(float2 a, float2 b) {  // a * conj(b)
    return make_float2(a.x * b.x + a.y * b.y, a.y * b.x - a.x * b.y);
}

__device__ __forceinline__ void bases_of(float px, float py, float pz,
                                         const float* __restrict__ inv,
                                         int base[3], float frac[3]) {
    float pr[3];
    pr[0] = (float)NSZ * (px * inv[0] + py * inv[3] + pz * inv[6]);
    pr[1] = (float)NSZ * (px * inv[1] + py * inv[4] + pz * inv[7]);
    pr[2] = (float)NSZ * (px * inv[2] + py * inv[5] + pz * inv[8]);
#pragma unroll
    for (int d = 0; d < 3; d++) {
        float b = floorf(pr[d]);
        frac[d] = pr[d] - b - 0.5f;
        int bi = (int)b;
        base[d] = bi < 0 ? 0 : (bi > NSZ - 1 ? NSZ - 1 : bi);
    }
}

__device__ __forceinline__ void weights_of(float x, float w[4]) {
    float x2 = x * x, x3 = x2 * x;
    w[0] = (1.0f - 6.0f * x + 12.0f * x2 - 8.0f * x3) * (1.0f / 48.0f);
    w[1] = (23.0f - 30.0f * x - 12.0f * x2 + 24.0f * x3) * (1.0f / 48.0f);
    w[2] = (23.0f + 30.0f * x - 12.0f * x2 - 24.0f * x3) * (1.0f / 48.0f);
    w[3] = (1.0f + 6.0f * x + 12.0f * x2 + 8.0f * x3) * (1.0f / 48.0f);
}

// single order-4 weight; o must be a compile-time constant at call sites (unrolled)
__device__ __forceinline__ float weight1(int o, float x) {
    float x2 = x * x, x3 = x2 * x;
    switch (o) {
        case 0:  return (1.0f - 6.0f * x + 12.0f * x2 - 8.0f * x3) * (1.0f / 48.0f);
        case 1:  return (23.0f - 30.0f * x - 12.0f * x2 + 24.0f * x3) * (1.0f / 48.0f);
        case 2:  return (23.0f + 30.0f * x - 12.0f * x2 - 24.0f * x3) * (1.0f / 48.0f);
        default: return (1.0f + 6.0f * x + 12.0f * x2 + 8.0f * x3) * (1.0f / 48.0f);
    }
}

__device__ __forceinline__ void stencil_pos(float px, float py, float pz,
                                            const float* __restrict__ inv,
                                            int base[3], float w[3][4]) {
    float frac[3];
    bases_of(px, py, pz, inv, base, frac);
    weights_of(frac[0], w[0]);
    weights_of(frac[1], w[1]);
    weights_of(frac[2], w[2]);
}

// ---------- binning: bucket (for gather) + column-chunk (for scatter) ----------

__global__ void bin_hist2(const float* __restrict__ pos, const float* __restrict__ cell,
                          int* __restrict__ counts, int* __restrict__ colcounts,
                          int n_atoms) {
    int a = blockIdx.x * blockDim.x + threadIdx.x;
    if (a >= n_atoms) return;
    float inv[9];
    inv3x3(cell, inv);
    int base[3];
    float frac[3];
    bases_of(pos[a * 3], pos[a * 3 + 1], pos[a * 3 + 2], inv, base, frac);
    int bucket = ((base[0] >> 3) * NBUCK_D + (base[1] >> 3)) * NBUCK_D + (base[2] >> 3);
    atomicAdd(&counts[bucket], 1);
    int ck = (base[0] * NSZ + base[1]) * NZC + (base[2] >> 4);
    atomicAdd(&colcounts[ck], 1);
}

__global__ void __launch_bounds__(1024)
scan4096(const int* __restrict__ counts, int* __restrict__ starts, int* __restrict__ cursor) {
    __shared__ int wsum[16];
    __shared__ int wpref[16];
    int t = threadIdx.x;
    int c0 = counts[4 * t], c1 = counts[4 * t + 1], c2 = counts[4 * t + 2], c3 = counts[4 * t + 3];
    int tot = c0 + c1 + c2 + c3;
    int lane = t & 63, w = t >> 6;
    int incl = tot;
#pragma unroll
    for (int o = 1; o < 64; o <<= 1) {
        int v = __shfl_up(incl, o, 64);
        if (lane >= o) incl += v;
    }
    if (lane == 63) wsum[w] = incl;
    __syncthreads();
    if (t < 16) {
        int p = 0;
        for (int i = 0; i < 16; i++) { if (i < t) p += wsum[i]; }
        wpref[t] = p;
    }
    __syncthreads();
    int ex = wpref[w] + incl - tot;
    starts[4 * t]     = ex;                cursor[4 * t]     = ex;
    starts[4 * t + 1] = ex + c0;           cursor[4 * t + 1] = ex + c0;
    starts[4 * t + 2] = ex + c0 + c1;      cursor[4 * t + 2] = ex + c0 + c1;
    starts[4 * t + 3] = ex + c0 + c1 + c2; cursor[4 * t + 3] = ex + c0 + c1 + c2;
    if (t == 1023) starts[4096] = ex + tot;
}

// 131072-element scan, 3 small kernels
__global__ void __launch_bounds__(1024)
colscanA(const int* __restrict__ cc, int* __restrict__ cs, int* __restrict__ sums) {
    __shared__ int wsum[16];
    __shared__ int wpref[16];
    int t = threadIdx.x;
    int i = blockIdx.x * 1024 + t;
    int c = cc[i];
    int lane = t & 63, w = t >> 6;
    int incl = c;
#pragma unroll
    for (int o = 1; o < 64; o <<= 1) {
        int v = __shfl_up(incl, o, 64);
        if (lane >= o) incl += v;
    }
    if (lane == 63) wsum[w] = incl;
    __syncthreads();
    if (t < 16) {
        int p = 0;
        for (int k = 0; k < 16; k++) { if (k < t) p += wsum[k]; }
        wpref[t] = p;
    }
    __syncthreads();
    int ex = wpref[w] + incl - c;
    cs[i] = ex;
    if (t == 1023) sums[blockIdx.x] = ex + c;
}

__global__ void __launch_bounds__(128)
colscanB(int* __restrict__ sums) {
    __shared__ int sd[128];
    int t = threadIdx.x;
    int v = sums[t];
    sd[t] = v;
    __syncthreads();
    for (int off = 1; off < 128; off <<= 1) {
        int x = (t >= off) ? sd[t - off] : 0;
        __syncthreads();
        sd[t] += x;
        __syncthreads();
    }
    sums[t] = sd[t] - v;          // exclusive
    if (t == 127) sums[128] = sd[127];
}

__global__ void __launch_bounds__(1024)
colscanC(int* __restrict__ cs, int* __restrict__ ccur, const int* __restrict__ sums) {
    int t = threadIdx.x;
    int i = blockIdx.x * 1024 + t;
    int v = cs[i] + sums[blockIdx.x];
    cs[i] = v;
    ccur[i] = v;
    if (blockIdx.x == 127 && t == 1023) cs[NCB] = sums[128];
}

// write both sorted record arrays
__global__ void bin_permute2(const float* __restrict__ pos, const float* __restrict__ cell,
                             const int* __restrict__ species, int* __restrict__ cursor,
                             float4* __restrict__ recs, int* __restrict__ colcursor,
                             float4* __restrict__ colrecs, int n_atoms) {
    int a = blockIdx.x * blockDim.x + threadIdx.x;
    if (a >= n_atoms) return;
    float inv[9];
    inv3x3(cell, inv);
    float px = pos[a * 3], py = pos[a * 3 + 1], pz = pos[a * 3 + 2];
    int base[3];
    float frac[3];
    bases_of(px, py, pz, inv, base, frac);
    int sp = species[a] & 1;
    int bucket = ((base[0] >> 3) * NBUCK_D + (base[1] >> 3)) * NBUCK_D + (base[2] >> 3);
    int p = atomicAdd(&cursor[bucket], 1);
    recs[p] = make_float4(px, py, pz, __int_as_float((a << 1) | sp));
    int ck = (base[0] * NSZ + base[1]) * NZC + (base[2] >> 4);
    int p2 = atomicAdd(&colcursor[ck], 1);
    int pack = base[0] | (base[1] << 7) | (base[2] << 14) | (sp << 21);
    colrecs[p2] = make_float4(frac[0], frac[1], frac[2], __int_as_float(pack));
}

// ---------- scatter: per-column register accumulation (NO atomics) ----------
// Block = 8^3 region (4096 blocks, 64 threads). Thread owns one z-column of 8
// cells x 2 species in registers; gathers contributions from the 4x4 neighbor
// columns' atoms (2 z-chunks each); one pure coalesced store.

__global__ void __launch_bounds__(64)
scatter_column(const int* __restrict__ colstarts, const float4* __restrict__ colrecs,
               float2* __restrict__ mesh) {
    int t = threadIdx.x;
    int lx = t >> 3, ly = t & 7;
    int sx = blockIdx.x << 3, sy = blockIdx.y << 3, sz = blockIdx.z << 3;
    int gxc = sx + lx, gyc = sy + ly;

    float accR[8], accI[8];
#pragma unroll
    for (int r = 0; r < 8; r++) { accR[r] = 0.0f; accI[r] = 0.0f; }

    int zc0 = ((sz - 2) & (NSZ - 1)) >> 4;
    int zc1 = ((sz + 8) & (NSZ - 1)) >> 4;

#pragma unroll
    for (int dx = 0; dx < 4; dx++) {
        int gx = (gxc - 2 + dx) & (NSZ - 1);
#pragma unroll
        for (int dy = 0; dy < 4; dy++) {
            int gy = (gyc - 2 + dy) & (NSZ - 1);
            int colbase = (gx * NSZ + gy) * NZC;
            for (int cc = 0; cc < 2; cc++) {
                int key = colbase + (cc ? zc1 : zc0);
                int s = colstarts[key], e = colstarts[key + 1];
                for (int i = s; i < e; i++) {
                    float4 a = colrecs[i];
                    int pk = __float_as_int(a.w);
                    int bz = (pk >> 14) & (NSZ - 1);
                    int zoff = (bz + 2 - sz) & (NSZ - 1);
                    if (zoff >= 11) continue;
                    float wxy = weight1(3 - dx, a.x) * weight1(3 - dy, a.y);
                    float wzs[4];
                    weights_of(a.z, wzs);
                    float spf = (float)((pk >> 21) & 1);
                    float wr = wxy * (1.0f - spf), wi = wxy * spf;
                    int zb = zoff - 3;   // lz = zb + dzc, dzc in [0,3]
#pragma unroll
                    for (int r = 0; r < 8; r++) {
                        int dzc = r - zb;
                        float wz = (dzc == 0) ? wzs[0]
                                 : (dzc == 1) ? wzs[1]
                                 : (dzc == 2) ? wzs[2] : wzs[3];
                        float wv = ((unsigned)dzc < 4u) ? wz : 0.0f;
                        accR[r] += wr * wv;
                        accI[r] += wi * wv;
                    }
                }
            }
        }
    }

    size_t cb = ((size_t)gxc * NSZ + gyc) * NSZ + sz;
#pragma unroll
    for (int r = 0; r < 8; r++) {
        mesh[cb + r] = make_float2(accR[r], accI[r]);
    }
}

// ---------- fallback atomic scatter (if ws too small) ----------

__global__ void scatter_atomic(const float* __restrict__ pos,
                               const float* __restrict__ cell,
                               const int* __restrict__ species,
                               float* __restrict__ meshf, int n_atoms) {
    int a = blockIdx.x * blockDim.x + threadIdx.x;
    if (a >= n_atoms) return;
    float inv[9];
    inv3x3(cell, inv);
    int base[3];
    float w[3][4];
    stencil_pos(pos[a * 3], pos[a * 3 + 1], pos[a * 3 + 2], inv, base, w);
    int sp = species[a] & 1;
#pragma unroll
    for (int l = 0; l < 4; l++) {
        int gx = (base[0] + l - 1 + NSZ) & (NSZ - 1);
#pragma unroll
        for (int m = 0; m < 4; m++) {
            int gy = (base[1] + m - 1 + NSZ) & (NSZ - 1);
            float wlm = w[0][l] * w[1][m];
            int rowb = (gx * NSZ + gy) * NSZ;
#pragma unroll
            for (int n = 0; n < 4; n++) {
                int gz = (base[2] + n - 1 + NSZ) & (NSZ - 1);
                atomicAdd(meshf + (((size_t)(rowb + gz)) << 1) + sp, wlm * w[2][n]);
            }
        }
    }
}

// ---------- fused FFT kernels ----------

__global__ void __launch_bounds__(1024)
fft_fwd_zy(float2* __restrict__ mesh) {
    extern __shared__ float2 sl[];
    __shared__ float2 tw[64];
    int t = threadIdx.x;
    int xs = blockIdx.x;
    if (t < 64) {
        float sn, cs;
        __sincosf(6.283185307179586f * (float)t / 128.0f, &sn, &cs);
        tw[t] = make_float2(cs, -sn);
    }
    const float4* src = (const float4*)(mesh + (size_t)xs * (NSZ * NSZ));
    for (int f = t; f < 8192; f += 1024) {
        float4 v = src[f];
        int y = f >> 6, z = (f & 63) * 2;
        sl[y * LROW + z]     = make_float2(v.x, v.y);
        sl[y * LROW + z + 1] = make_float2(v.z, v.w);
    }
    __syncthreads();
    int lane = t & 127, jb = (t >> 7) * 8;
    for (int s = 6; s >= 0; --s) {
        int half = 1 << s;
        for (int j = jb; j < jb + 8; ++j) {
            int pos = j & (half - 1);
            int i0 = ((j >> s) << (s + 1)) + pos;
            float2 w = tw[pos << (6 - s)];
            float2* p0 = &sl[lane * LROW + i0];
            float2 a = p0[0], b = p0[half];
            p0[0]    = cadd(a, b);
            p0[half] = cmul(csub(a, b), w);
        }
        __syncthreads();
    }
    for (int s = 6; s >= 0; --s) {
        int half = 1 << s;
        for (int j = jb; j < jb + 8; ++j) {
            int pos = j & (half - 1);
            int i0 = ((j >> s) << (s + 1)) + pos;
            float2 w = tw[pos << (6 - s)];
            float2* p0 = &sl[i0 * LROW + lane];
            float2 a = p0[0], b = p0[half * LROW];
            p0[0]           = cadd(a, b);
            p0[half * LROW] = cmul(csub(a, b), w);
        }
        __syncthreads();
    }
    float4* dst = (float4*)(mesh + (size_t)xs * (NSZ * NSZ));
    for (int f = t; f < 8192; f += 1024) {
        int y = f >> 6, z = (f & 63) * 2;
        float2 u0 = sl[y * LROW + z], u1 = sl[y * LROW + z + 1];
        dst[f] = make_float4(u0.x, u0.y, u1.x, u1.y);
    }
}

__global__ void __launch_bounds__(1024)
fft_x_g(float2* __restrict__ mesh, const float* __restrict__ cell, float smearing) {
    extern __shared__ float2 sl[];
    __shared__ float2 tw[64];
    int t = threadIdx.x;
    int y = blockIdx.x;
    if (t < 64) {
        float sn, cs;
        __sincosf(6.283185307179586f * (float)t / 128.0f, &sn, &cs);
        tw[t] = make_float2(cs, -sn);
    }
    for (int f = t; f < 8192; f += 1024) {
        int x = f >> 6, c = f & 63;
        float4 v = ((const float4*)mesh)[(size_t)x * 8192 + (size_t)y * 64 + c];
        int z = c * 2;
        sl[x * LROW + z]     = make_float2(v.x, v.y);
        sl[x * LROW + z + 1] = make_float2(v.z, v.w);
    }
    __syncthreads();
    int lane = t & 127, jb = (t >> 7) * 8;
    for (int s = 6; s >= 0; --s) {
        int half = 1 << s;
        for (int j = jb; j < jb + 8; ++j) {
            int pos = j & (half - 1);
            int i0 = ((j >> s) << (s + 1)) + pos;
            float2 w = tw[pos << (6 - s)];
            float2* p0 = &sl[i0 * LROW + lane];
            float2 a = p0[0], b = p0[half * LROW];
            p0[0]           = cadd(a, b);
            p0[half * LROW] = cmul(csub(a, b), w);
        }
        __syncthreads();
    }
    {
        float inv[9];
        inv3x3(cell, inv);
        float vol = fabsf(det3x3(cell));
        int kyi = brev7(y);
        float fy = (kyi < NSZ / 2) ? (float)kyi : (float)(kyi - NSZ);
        const float twopi = 6.283185307179586f;
        for (int f = t; f < NSZ * NSZ; f += 1024) {
            int px = f >> 7, pz = f & 127;
            int kxi = brev7(px), kzi = brev7(pz);
            float fx = (kxi < NSZ / 2) ? (float)kxi : (float)(kxi - NSZ);
            float fz = (kzi < NSZ / 2) ? (float)kzi : (float)(kzi - NSZ);
            float k0 = twopi * (fx * inv[0] + fy * inv[1] + fz * inv[2]);
            float k1 = twopi * (fx * inv[3] + fy * inv[4] + fz * inv[5]);
            float k2 = twopi * (fx * inv[6] + fy * inv[7] + fz * inv[8]);
            float ksq = k0 * k0 + k1 * k1 + k2 * k2;
            float g = 0.0f;
            if (ksq > 0.0f) {
                g = 12.566370614359172f * __expf(-0.5f * smearing * smearing * ksq) / ksq;
            }
            g /= vol;
            float2 v = sl[px * LROW + pz];
            sl[px * LROW + pz] = make_float2(v.x * g, v.y * g);
        }
    }
    __syncthreads();
    for (int s = 0; s < 7; ++s) {
        int half = 1 << s;
        for (int j = jb; j < jb + 8; ++j) {
            int pos = j & (half - 1);
            int i0 = ((j >> s) << (s + 1)) + pos;
            float2 w = tw[pos << (6 - s)];
            float2* p0 = &sl[i0 * LROW + lane];
            float2 a = p0[0];
            float2 bw = cmulc(p0[half * LROW], w);
            p0[0]           = cadd(a, bw);
            p0[half * LROW] = csub(a, bw);
        }
        __syncthreads();
    }
    for (int f = t; f < 8192; f += 1024) {
        int x = f >> 6, c = f & 63;
        int z = c * 2;
        float2 u0 = sl[x * LROW + z], u1 = sl[x * LROW + z + 1];
        ((float4*)mesh)[(size_t)x * 8192 + (size_t)y * 64 + c] = make_float4(u0.x, u0.y, u1.x, u1.y);
    }
}

__global__ void __launch_bounds__(1024)
fft_inv_yz(float2* __restrict__ mesh) {
    extern __shared__ float2 sl[];
    __shared__ float2 tw[64];
    int t = threadIdx.x;
    int xs = blockIdx.x;
    if (t < 64) {
        float sn, cs;
        __sincosf(6.283185307179586f * (float)t / 128.0f, &sn, &cs);
        tw[t] = make_float2(cs, -sn);
    }
    const float4* src = (const float4*)(mesh + (size_t)xs * (NSZ * NSZ));
    for (int f = t; f < 8192; f += 1024) {
        float4 v = src[f];
        int y = f >> 6, z = (f & 63) * 2;
        sl[y * LROW + z]     = make_float2(v.x, v.y);
        sl[y * LROW + z + 1] = make_float2(v.z, v.w);
    }
    __syncthreads();
    int lane = t & 127, jb = (t >> 7) * 8;
    for (int s = 0; s < 7; ++s) {
        int half = 1 << s;
        for (int j = jb; j < jb + 8; ++j) {
            int pos = j & (half - 1);
            int i0 = ((j >> s) << (s + 1)) + pos;
            float2 w = tw[pos << (6 - s)];
            float2* p0 = &sl[i0 * LROW + lane];
            float2 a = p0[0];
            float2 bw = cmulc(p0[half * LROW], w);
            p0[0]           = cadd(a, bw);
            p0[half * LROW] = csub(a, bw);
        }
        __syncthreads();
    }
    for (int s = 0; s < 7; ++s) {
        int half = 1 << s;
        for (int j = jb; j < jb + 8; ++j) {
            int pos = j & (half - 1);
            int i0 = ((j >> s) << (s + 1)) + pos;
            float2 w = tw[pos << (6 - s)];
            float2* p0 = &sl[lane * LROW + i0];
            float2 a = p0[0];
            float2 bw = cmulc(p0[half], w);
            p0[0]    = cadd(a, bw);
            p0[half] = csub(a, bw);
        }
        __syncthreads();
    }
    float4* dst = (float4*)(mesh + (size_t)xs * (NSZ * NSZ));
    for (int f = t; f < 8192; f += 1024) {
        int y = f >> 6, z = (f & 63) * 2;
        float2 u0 = sl[y * LROW + z], u1 = sl[y * LROW + z + 1];
        dst[f] = make_float4(u0.x, u0.y, u1.x, u1.y);
    }
}

// ---------- gather: per-bucket LDS-staged, one thread per atom ----------

#define GROW 12   // padded z-row for gather LDS (11 used)

__global__ void __launch_bounds__(128)
gather_region(const float* __restrict__ cell, const int* __restrict__ starts,
              const float4* __restrict__ recs, const float2* __restrict__ mesh,
              float2* __restrict__ out) {
    __shared__ float2 gm[11 * 11 * GROW];
    int t = threadIdx.x;
    int b = blockIdx.x;
    int bx = b >> 8, by = (b >> 4) & 15, bz = b & 15;
    int ox = bx * 8 - 1, oy = by * 8 - 1, oz = bz * 8 - 1;

    for (int i = t; i < 11 * 11 * 11; i += 128) {
        int x = i / 121, rem = i % 121, y = rem / 11, z = rem % 11;
        int gx = (ox + x) & (NSZ - 1);
        int gy = (oy + y) & (NSZ - 1);
        int gz = (oz + z) & (NSZ - 1);
        gm[(x * 11 + y) * GROW + z] = mesh[(size_t)(gx * NSZ + gy) * NSZ + gz];
    }
    __syncthreads();

    int s = starts[b], e = starts[b + 1];
    float inv[9];
    inv3x3(cell, inv);

    for (int ai = s + t; ai < e; ai += 128) {
        float4 rec = recs[ai];
        int base[3];
        float w[3][4];
        stencil_pos(rec.x, rec.y, rec.z, inv, base, w);
        int lx0 = base[0] - bx * 8;
        int ly0 = base[1] - by * 8;
        int lz0 = base[2] - bz * 8;
        float acc0 = 0.0f, acc1 = 0.0f;
#pragma unroll
        for (int l = 0; l < 4; l++) {
            float wl = w[0][l];
#pragma unroll
            for (int m = 0; m < 4; m++) {
                float wlm = wl * w[1][m];
                int rowb = ((lx0 + l) * 11 + (ly0 + m)) * GROW + lz0;
#pragma unroll
                for (int n = 0; n < 4; n++) {
                    float2 v = gm[rowb + n];
                    float ww = wlm * w[2][n];
                    acc0 += ww * v.x;
                    acc1 += ww * v.y;
                }
            }
        }
        out[__float_as_int(rec.w) >> 1] = make_float2(acc0, acc1);
    }
}

__global__ void gather_plain(const float* __restrict__ pos,
                             const float* __restrict__ cell,
                             const float2* __restrict__ mesh,
                             float2* __restrict__ out, int n_atoms) {
    int a = blockIdx.x * blockDim.x + threadIdx.x;
    if (a >= n_atoms) return;
    float inv[9];
    inv3x3(cell, inv);
    int base[3];
    float w[3][4];
    stencil_pos(pos[a * 3], pos[a * 3 + 1], pos[a * 3 + 2], inv, base, w);
    float acc0 = 0.0f, acc1 = 0.0f;
#pragma unroll
    for (int l = 0; l < 4; l++) {
        int gx = (base[0] + l - 1 + NSZ) & (NSZ - 1);
#pragma unroll
        for (int m = 0; m < 4; m++) {
            int gy = (base[1] + m - 1 + NSZ) & (NSZ - 1);
            float wlm = w[0][l] * w[1][m];
            int rowb = (gx * NSZ + gy) * NSZ;
#pragma unroll
            for (int n = 0; n < 4; n++) {
                int gz = (base[2] + n - 1 + NSZ) & (NSZ - 1);
                float2 v = mesh[rowb + gz];
                float ww = wlm * w[2][n];
                acc0 += ww * v.x;
                acc1 += ww * v.y;
            }
        }
    }
    out[a] = make_float2(acc0, acc1);
}

// ---------- launch ----------

extern "C" void kernel_launch(void* const* d_in, const int* in_sizes, int n_in,
                              void* d_out, int out_size, void* d_ws, size_t ws_size,
                              hipStream_t stream) {
    const float* pos     = (const float*)d_in[0];
    const float* cell    = (const float*)d_in[1];
    const int*   species = (const int*)d_in[2];
    int n_atoms = in_sizes[0] / 3;

    // workspace layout
    char* ws = (char*)d_ws;
    float2* mesh = (float2*)ws;                                   // 16 MiB
    size_t off = (size_t)NS3 * sizeof(float2);
    int* counts    = (int*)(ws + off);        off += NBUCK * 4;       // zeroed
    int* colcounts = (int*)(ws + off);        off += NCB * 4;         // zeroed (adjacent)
    int* starts    = (int*)(ws + off);        off += (NBUCK + 4) * 4;
    int* cursor    = (int*)(ws + off);        off += NBUCK * 4;
    int* colstarts = (int*)(ws + off);        off += (NCB + 4) * 4;
    int* colcursor = (int*)(ws + off);        off += NCB * 4;
    int* colsums   = (int*)(ws + off);        off += 132 * 4;
    off = (off + 15) & ~(size_t)15;
    float4* recs    = (float4*)(ws + off);    off += (size_t)n_atoms * 16;
    float4* colrecs = (float4*)(ws + off);    off += (size_t)n_atoms * 16;
    bool binned = (ws_size >= off);

    hipFuncSetAttribute((const void*)fft_fwd_zy, hipFuncAttributeMaxDynamicSharedMemorySize, (int)LDS_BYTES);
    hipFuncSetAttribute((const void*)fft_x_g,    hipFuncAttributeMaxDynamicSharedMemorySize, (int)LDS_BYTES);
    hipFuncSetAttribute((const void*)fft_inv_yz, hipFuncAttributeMaxDynamicSharedMemorySize, (int)LDS_BYTES);

    int ab = (n_atoms + 255) / 256;

    if (binned) {
        hipMemsetAsync(counts, 0, (NBUCK + NCB) * 4, stream);   // counts + colcounts
        bin_hist2<<<ab, 256, 0, stream>>>(pos, cell, counts, colcounts, n_atoms);
        scan4096<<<1, 1024, 0, stream>>>(counts, starts, cursor);
        colscanA<<<128, 1024, 0, stream>>>(colcounts, colstarts, colsums);
        colscanB<<<1, 128, 0, stream>>>(colsums);
        colscanC<<<128, 1024, 0, stream>>>(colstarts, colcursor, colsums);
        bin_permute2<<<ab, 256, 0, stream>>>(pos, cell, species, cursor, recs,
                                             colcursor, colrecs, n_atoms);
        dim3 rg(NSZ / 8, NSZ / 8, NSZ / 8);
        scatter_column<<<rg, 64, 0, stream>>>(colstarts, colrecs, mesh);
    } else {
        hipMemsetAsync(mesh, 0, (size_t)NS3 * sizeof(float2), stream);
        scatter_atomic<<<ab, 256, 0, stream>>>(pos, cell, species, (float*)mesh, n_atoms);
    }

    fft_fwd_zy<<<NSZ, 1024, LDS_BYTES, stream>>>(mesh);
    fft_x_g   <<<NSZ, 1024, LDS_BYTES, stream>>>(mesh, cell, 1.0f /* SMEARING */);
    fft_inv_yz<<<NSZ, 1024, LDS_BYTES, stream>>>(mesh);

    if (binned) {
        gather_region<<<NBUCK, 128, 0, stream>>>(cell, starts, recs, mesh, (float2*)d_out);
    } else {
        gather_plain<<<ab, 256, 0, stream>>>(pos, cell, mesh, (float2*)d_out, n_atoms);
    }
}

// Round 12
// 238.777 us; speedup vs baseline: 1.3252x; 1.3252x over previous
//
#include <hip/hip_runtime.h>

#define NSZ 128
#define NS3 (NSZ * NSZ * NSZ)
#define NBUCK 4096           // x-cell-major buckets: xcell*32 + (ycell>>2)
#define LROW 129             // padded LDS row stride (complex) for FFT planes
#define LDS_BYTES (NSZ * LROW * sizeof(float2))   // 132096

// ---------- small helpers ----------

__device__ __forceinline__ void inv3x3(const float* __restrict__ c, float* inv) {
    float a00 = c[0], a01 = c[1], a02 = c[2];
    float a10 = c[3], a11 = c[4], a12 = c[5];
    float a20 = c[6], a21 = c[7], a22 = c[8];
    float det = a00 * (a11 * a22 - a12 * a21)
              - a01 * (a10 * a22 - a12 * a20)
              + a02 * (a10 * a21 - a11 * a20);
    float id = 1.0f / det;
    inv[0] = (a11 * a22 - a12 * a21) * id;
    inv[1] = (a02 * a21 - a01 * a22) * id;
    inv[2] = (a01 * a12 - a02 * a11) * id;
    inv[3] = (a12 * a20 - a10 * a22) * id;
    inv[4] = (a00 * a22 - a02 * a20) * id;
    inv[5] = (a02 * a10 - a00 * a12) * id;
    inv[6] = (a10 * a21 - a11 * a20) * id;
    inv[7] = (a01 * a20 - a00 * a21) * id;
    inv[8] = (a00 * a11 - a01 * a10) * id;
}

__device__ __forceinline__ float det3x3(const float* __restrict__ c) {
    return c[0] * (c[4] * c[8] - c[5] * c[7])
         - c[1] * (c[3] * c[8] - c[5] * c[6])
         + c[2] * (c[3] * c[7] - c[4] * c[6]);
}

__device__ __forceinline__ int brev7(int i) { return (int)(__brev((unsigned)i) >> 25); }

__device__ __forceinline__ float2 cadd(float2 a, float2 b) { return make_float2(a.x + b.x, a.y + b.y); }
__device__ __forceinline__ float2 csub(float2 a, float2 b) { return make_float2(a.x - b.x, a.y - b.y); }
__device__ __forceinline__ float2 cmul(float2 a, float2 b) {
    return make_float2(a.x * b.x - a.y * b.y, a.x * b.y + a.y * b.x);
}
__device__ __forceinline__ float2 cmulc(float2 a, float2 b) {  // a * conj(b)
    return make_float2(a.x * b.x + a.y * b.y, a.y * b.x - a.x * b.y);
}

__device__ __forceinline__ void bases_of(float px, float py, float pz,
                                         const float* __restrict__ inv,
                                         int base[3], float frac[3]) {
    float pr[3];
    pr[0] = (float)NSZ * (px * inv[0] + py * inv[3] + pz * inv[6]);
    pr[1] = (float)NSZ * (px * inv[1] + py * inv[4] + pz * inv[7]);
    pr[2] = (float)NSZ * (px * inv[2] + py * inv[5] + pz * inv[8]);
#pragma unroll
    for (int d = 0; d < 3; d++) {
        float b = floorf(pr[d]);
        frac[d] = pr[d] - b - 0.5f;
        int bi = (int)b;
        base[d] = bi < 0 ? 0 : (bi > NSZ - 1 ? NSZ - 1 : bi);
    }
}

__device__ __forceinline__ void weights_of(float x, float w[4]) {
    float x2 = x * x, x3 = x2 * x;
    w[0] = (1.0f - 6.0f * x + 12.0f * x2 - 8.0f * x3) * (1.0f / 48.0f);
    w[1] = (23.0f - 30.0f * x - 12.0f * x2 + 24.0f * x3) * (1.0f / 48.0f);
    w[2] = (23.0f + 30.0f * x - 12.0f * x2 - 24.0f * x3) * (1.0f / 48.0f);
    w[3] = (1.0f + 6.0f * x + 12.0f * x2 + 8.0f * x3) * (1.0f / 48.0f);
}

// single order-4 weight; o is a compile-time constant at call sites
__device__ __forceinline__ float weight1(int o, float x) {
    float x2 = x * x, x3 = x2 * x;
    switch (o) {
        case 0:  return (1.0f - 6.0f * x + 12.0f * x2 - 8.0f * x3) * (1.0f / 48.0f);
        case 1:  return (23.0f - 30.0f * x - 12.0f * x2 + 24.0f * x3) * (1.0f / 48.0f);
        case 2:  return (23.0f + 30.0f * x - 12.0f * x2 - 24.0f * x3) * (1.0f / 48.0f);
        default: return (1.0f + 6.0f * x + 12.0f * x2 + 8.0f * x3) * (1.0f / 48.0f);
    }
}

__device__ __forceinline__ void stencil_pos(float px, float py, float pz,
                                            const float* __restrict__ inv,
                                            int base[3], float w[3][4]) {
    float frac[3];
    bases_of(px, py, pz, inv, base, frac);
    weights_of(frac[0], w[0]);
    weights_of(frac[1], w[1]);
    weights_of(frac[2], w[2]);
}

// ---------- binning: x-cell-major sort ----------

__device__ __forceinline__ int xkey_of(const int base[3]) {
    return base[0] * 32 + (base[1] >> 2);
}

__global__ void bin_hist(const float* __restrict__ pos, const float* __restrict__ cell,
                         int* __restrict__ counts, int n_atoms) {
    int a = blockIdx.x * blockDim.x + threadIdx.x;
    if (a >= n_atoms) return;
    float inv[9];
    inv3x3(cell, inv);
    int base[3];
    float frac[3];
    bases_of(pos[a * 3], pos[a * 3 + 1], pos[a * 3 + 2], inv, base, frac);
    atomicAdd(&counts[xkey_of(base)], 1);
}

__global__ void __launch_bounds__(1024)
scan4096(const int* __restrict__ counts, int* __restrict__ starts, int* __restrict__ cursor) {
    __shared__ int wsum[16];
    __shared__ int wpref[16];
    int t = threadIdx.x;
    int c0 = counts[4 * t], c1 = counts[4 * t + 1], c2 = counts[4 * t + 2], c3 = counts[4 * t + 3];
    int tot = c0 + c1 + c2 + c3;
    int lane = t & 63, w = t >> 6;
    int incl = tot;
#pragma unroll
    for (int o = 1; o < 64; o <<= 1) {
        int v = __shfl_up(incl, o, 64);
        if (lane >= o) incl += v;
    }
    if (lane == 63) wsum[w] = incl;
    __syncthreads();
    if (t < 16) {
        int p = 0;
        for (int i = 0; i < 16; i++) { if (i < t) p += wsum[i]; }
        wpref[t] = p;
    }
    __syncthreads();
    int ex = wpref[w] + incl - tot;
    starts[4 * t]     = ex;                cursor[4 * t]     = ex;
    starts[4 * t + 1] = ex + c0;           cursor[4 * t + 1] = ex + c0;
    starts[4 * t + 2] = ex + c0 + c1;      cursor[4 * t + 2] = ex + c0 + c1;
    starts[4 * t + 3] = ex + c0 + c1 + c2; cursor[4 * t + 3] = ex + c0 + c1 + c2;
    if (t == 1023) starts[4096] = ex + tot;
}

// sorted records: (frac0, frac1, frac2, pack = bx | by<<7 | bz<<14 | sp<<21); ids[p] = atom id
__global__ void bin_permute(const float* __restrict__ pos, const float* __restrict__ cell,
                            const int* __restrict__ species, int* __restrict__ cursor,
                            float4* __restrict__ recs, int* __restrict__ ids, int n_atoms) {
    int a = blockIdx.x * blockDim.x + threadIdx.x;
    if (a >= n_atoms) return;
    float inv[9];
    inv3x3(cell, inv);
    int base[3];
    float frac[3];
    bases_of(pos[a * 3], pos[a * 3 + 1], pos[a * 3 + 2], inv, base, frac);
    int sp = species[a] & 1;
    int p = atomicAdd(&cursor[xkey_of(base)], 1);
    int pack = base[0] | (base[1] << 7) | (base[2] << 14) | (sp << 21);
    recs[p] = make_float4(frac[0], frac[1], frac[2], __int_as_float(pack));
    ids[p] = a;
}

// ---------- fused: scatter (into LDS plane) + forward z/y FFT per x-slab ----------

__global__ void __launch_bounds__(1024)
fft_fwd_zy_sc(const float4* __restrict__ recs, const int* __restrict__ starts,
              float2* __restrict__ mesh) {
    extern __shared__ float2 sl[];
    __shared__ float2 tw[64];
    int t = threadIdx.x;
    int xs = blockIdx.x;
    if (t < 64) {
        float sn, cs;
        __sincosf(6.283185307179586f * (float)t / 128.0f, &sn, &cs);
        tw[t] = make_float2(cs, -sn);
    }
    for (int i = t; i < NSZ * LROW; i += 1024) sl[i] = make_float2(0.0f, 0.0f);
    __syncthreads();

    // scatter: 4 x-cell ranges touch this slab; range k has wx index l = 3-k
    float* pf = (float*)sl;
#pragma unroll
    for (int k = 0; k < 4; k++) {
        int bx = (xs - 2 + k) & (NSZ - 1);
        int s = starts[bx * 32], e = starts[bx * 32 + 32];
        for (int i = s + t; i < e; i += 1024) {
            float4 r = recs[i];
            int pk = __float_as_int(r.w);
            int by = (pk >> 7) & 127, bz = (pk >> 14) & 127, sp = (pk >> 21) & 1;
            float wx = weight1(3 - k, r.x);
            float wy[4], wz[4];
            weights_of(r.y, wy);
            weights_of(r.z, wz);
#pragma unroll
            for (int m = 0; m < 4; m++) {
                int gy = (by - 1 + m) & (NSZ - 1);
                float wxm = wx * wy[m];
#pragma unroll
                for (int n = 0; n < 4; n++) {
                    int gz = (bz - 1 + n) & (NSZ - 1);
                    atomicAdd(pf + ((gy * LROW + gz) << 1) + sp, wxm * wz[n]);
                }
            }
        }
    }
    __syncthreads();

    int lane = t & 127, jb = (t >> 7) * 8;
    for (int s = 6; s >= 0; --s) {            // z-axis DIF
        int half = 1 << s;
        for (int j = jb; j < jb + 8; ++j) {
            int pos = j & (half - 1);
            int i0 = ((j >> s) << (s + 1)) + pos;
            float2 w = tw[pos << (6 - s)];
            float2* p0 = &sl[lane * LROW + i0];
            float2 a = p0[0], b = p0[half];
            p0[0]    = cadd(a, b);
            p0[half] = cmul(csub(a, b), w);
        }
        __syncthreads();
    }
    for (int s = 6; s >= 0; --s) {            // y-axis DIF
        int half = 1 << s;
        for (int j = jb; j < jb + 8; ++j) {
            int pos = j & (half - 1);
            int i0 = ((j >> s) << (s + 1)) + pos;
            float2 w = tw[pos << (6 - s)];
            float2* p0 = &sl[i0 * LROW + lane];
            float2 a = p0[0], b = p0[half * LROW];
            p0[0]           = cadd(a, b);
            p0[half * LROW] = cmul(csub(a, b), w);
        }
        __syncthreads();
    }
    float4* dst = (float4*)(mesh + (size_t)xs * (NSZ * NSZ));
    for (int f = t; f < 8192; f += 1024) {
        int y = f >> 6, z = (f & 63) * 2;
        float2 u0 = sl[y * LROW + z], u1 = sl[y * LROW + z + 1];
        dst[f] = make_float4(u0.x, u0.y, u1.x, u1.y);
    }
}

// ---------- x-FFT + G + inverse x-FFT per y-plane (unchanged) ----------

__global__ void __launch_bounds__(1024)
fft_x_g(float2* __restrict__ mesh, const float* __restrict__ cell, float smearing) {
    extern __shared__ float2 sl[];
    __shared__ float2 tw[64];
    int t = threadIdx.x;
    int y = blockIdx.x;
    if (t < 64) {
        float sn, cs;
        __sincosf(6.283185307179586f * (float)t / 128.0f, &sn, &cs);
        tw[t] = make_float2(cs, -sn);
    }
    for (int f = t; f < 8192; f += 1024) {
        int x = f >> 6, c = f & 63;
        float4 v = ((const float4*)mesh)[(size_t)x * 8192 + (size_t)y * 64 + c];
        int z = c * 2;
        sl[x * LROW + z]     = make_float2(v.x, v.y);
        sl[x * LROW + z + 1] = make_float2(v.z, v.w);
    }
    __syncthreads();
    int lane = t & 127, jb = (t >> 7) * 8;
    for (int s = 6; s >= 0; --s) {
        int half = 1 << s;
        for (int j = jb; j < jb + 8; ++j) {
            int pos = j & (half - 1);
            int i0 = ((j >> s) << (s + 1)) + pos;
            float2 w = tw[pos << (6 - s)];
            float2* p0 = &sl[i0 * LROW + lane];
            float2 a = p0[0], b = p0[half * LROW];
            p0[0]           = cadd(a, b);
            p0[half * LROW] = cmul(csub(a, b), w);
        }
        __syncthreads();
    }
    {
        float inv[9];
        inv3x3(cell, inv);
        float vol = fabsf(det3x3(cell));
        int kyi = brev7(y);
        float fy = (kyi < NSZ / 2) ? (float)kyi : (float)(kyi - NSZ);
        const float twopi = 6.283185307179586f;
        for (int f = t; f < NSZ * NSZ; f += 1024) {
            int px = f >> 7, pz = f & 127;
            int kxi = brev7(px), kzi = brev7(pz);
            float fx = (kxi < NSZ / 2) ? (float)kxi : (float)(kxi - NSZ);
            float fz = (kzi < NSZ / 2) ? (float)kzi : (float)(kzi - NSZ);
            float k0 = twopi * (fx * inv[0] + fy * inv[1] + fz * inv[2]);
            float k1 = twopi * (fx * inv[3] + fy * inv[4] + fz * inv[5]);
            float k2 = twopi * (fx * inv[6] + fy * inv[7] + fz * inv[8]);
            float ksq = k0 * k0 + k1 * k1 + k2 * k2;
            float g = 0.0f;
            if (ksq > 0.0f) {
                g = 12.566370614359172f * __expf(-0.5f * smearing * smearing * ksq) / ksq;
            }
            g /= vol;
            float2 v = sl[px * LROW + pz];
            sl[px * LROW + pz] = make_float2(v.x * g, v.y * g);
        }
    }
    __syncthreads();
    for (int s = 0; s < 7; ++s) {
        int half = 1 << s;
        for (int j = jb; j < jb + 8; ++j) {
            int pos = j & (half - 1);
            int i0 = ((j >> s) << (s + 1)) + pos;
            float2 w = tw[pos << (6 - s)];
            float2* p0 = &sl[i0 * LROW + lane];
            float2 a = p0[0];
            float2 bw = cmulc(p0[half * LROW], w);
            p0[0]           = cadd(a, bw);
            p0[half * LROW] = csub(a, bw);
        }
        __syncthreads();
    }
    for (int f = t; f < 8192; f += 1024) {
        int x = f >> 6, c = f & 63;
        int z = c * 2;
        float2 u0 = sl[x * LROW + z], u1 = sl[x * LROW + z + 1];
        ((float4*)mesh)[(size_t)x * 8192 + (size_t)y * 64 + c] = make_float4(u0.x, u0.y, u1.x, u1.y);
    }
}

// ---------- fused: inverse y/z FFT + gather (per-slab partials) ----------

__global__ void __launch_bounds__(1024)
fft_inv_yz_ga(const float4* __restrict__ recs, const int* __restrict__ starts,
              const float2* __restrict__ mesh, float2* __restrict__ partials) {
    extern __shared__ float2 sl[];
    __shared__ float2 tw[64];
    int t = threadIdx.x;
    int xs = blockIdx.x;
    if (t < 64) {
        float sn, cs;
        __sincosf(6.283185307179586f * (float)t / 128.0f, &sn, &cs);
        tw[t] = make_float2(cs, -sn);
    }
    const float4* src = (const float4*)(mesh + (size_t)xs * (NSZ * NSZ));
    for (int f = t; f < 8192; f += 1024) {
        float4 v = src[f];
        int y = f >> 6, z = (f & 63) * 2;
        sl[y * LROW + z]     = make_float2(v.x, v.y);
        sl[y * LROW + z + 1] = make_float2(v.z, v.w);
    }
    __syncthreads();
    int lane = t & 127, jb = (t >> 7) * 8;
    for (int s = 0; s < 7; ++s) {             // y-axis DIT inverse
        int half = 1 << s;
        for (int j = jb; j < jb + 8; ++j) {
            int pos = j & (half - 1);
            int i0 = ((j >> s) << (s + 1)) + pos;
            float2 w = tw[pos << (6 - s)];
            float2* p0 = &sl[i0 * LROW + lane];
            float2 a = p0[0];
            float2 bw = cmulc(p0[half * LROW], w);
            p0[0]           = cadd(a, bw);
            p0[half * LROW] = csub(a, bw);
        }
        __syncthreads();
    }
    for (int s = 0; s < 7; ++s) {             // z-axis DIT inverse
        int half = 1 << s;
        for (int j = jb; j < jb + 8; ++j) {
            int pos = j & (half - 1);
            int i0 = ((j >> s) << (s + 1)) + pos;
            float2 w = tw[pos << (6 - s)];
            float2* p0 = &sl[lane * LROW + i0];
            float2 a = p0[0];
            float2 bw = cmulc(p0[half], w);
            p0[0]    = cadd(a, bw);
            p0[half] = csub(a, bw);
        }
        __syncthreads();
    }

    // gather: same 4 ranges; partial for wx index l = 3-k, slot = i*4 + l
#pragma unroll
    for (int k = 0; k < 4; k++) {
        int bx = (xs - 2 + k) & (NSZ - 1);
        int s = starts[bx * 32], e = starts[bx * 32 + 32];
        for (int i = s + t; i < e; i += 1024) {
            float4 r = recs[i];
            int pk = __float_as_int(r.w);
            int by = (pk >> 7) & 127, bz = (pk >> 14) & 127;
            float wx = weight1(3 - k, r.x);
            float wy[4], wz[4];
            weights_of(r.y, wy);
            weights_of(r.z, wz);
            float a0 = 0.0f, a1 = 0.0f;
#pragma unroll
            for (int m = 0; m < 4; m++) {
                int gy = (by - 1 + m) & (NSZ - 1);
                int rowb = gy * LROW;
#pragma unroll
                for (int n = 0; n < 4; n++) {
                    int gz = (bz - 1 + n) & (NSZ - 1);
                    float2 v = sl[rowb + gz];
                    float ww = wy[m] * wz[n];
                    a0 += ww * v.x;
                    a1 += ww * v.y;
                }
            }
            partials[(size_t)i * 4 + (3 - k)] = make_float2(wx * a0, wx * a1);
        }
    }
}

// ---------- combine partials -> output ----------

__global__ void combine(const float2* __restrict__ partials, const int* __restrict__ ids,
                        float2* __restrict__ out, int n_atoms) {
    int i = blockIdx.x * blockDim.x + threadIdx.x;
    if (i >= n_atoms) return;
    float2 p0 = partials[4 * i], p1 = partials[4 * i + 1];
    float2 p2 = partials[4 * i + 2], p3 = partials[4 * i + 3];
    out[ids[i]] = make_float2(p0.x + p1.x + p2.x + p3.x,
                              p0.y + p1.y + p2.y + p3.y);
}

// ---------- fallback path (ws too small): atomic scatter + plain FFTs + plain gather ----------

__global__ void scatter_atomic(const float* __restrict__ pos,
                               const float* __restrict__ cell,
                               const int* __restrict__ species,
                               float* __restrict__ meshf, int n_atoms) {
    int a = blockIdx.x * blockDim.x + threadIdx.x;
    if (a >= n_atoms) return;
    float inv[9];
    inv3x3(cell, inv);
    int base[3];
    float w[3][4];
    stencil_pos(pos[a * 3], pos[a * 3 + 1], pos[a * 3 + 2], inv, base, w);
    int sp = species[a] & 1;
#pragma unroll
    for (int l = 0; l < 4; l++) {
        int gx = (base[0] + l - 1 + NSZ) & (NSZ - 1);
#pragma unroll
        for (int m = 0; m < 4; m++) {
            int gy = (base[1] + m - 1 + NSZ) & (NSZ - 1);
            float wlm = w[0][l] * w[1][m];
            int rowb = (gx * NSZ + gy) * NSZ;
#pragma unroll
            for (int n = 0; n < 4; n++) {
                int gz = (base[2] + n - 1 + NSZ) & (NSZ - 1);
                atomicAdd(meshf + (((size_t)(rowb + gz)) << 1) + sp, wlm * w[2][n]);
            }
        }
    }
}

__global__ void __launch_bounds__(1024)
fft_fwd_zy(float2* __restrict__ mesh) {
    extern __shared__ float2 sl[];
    __shared__ float2 tw[64];
    int t = threadIdx.x;
    int xs = blockIdx.x;
    if (t < 64) {
        float sn, cs;
        __sincosf(6.283185307179586f * (float)t / 128.0f, &sn, &cs);
        tw[t] = make_float2(cs, -sn);
    }
    const float4* src = (const float4*)(mesh + (size_t)xs * (NSZ * NSZ));
    for (int f = t; f < 8192; f += 1024) {
        float4 v = src[f];
        int y = f >> 6, z = (f & 63) * 2;
        sl[y * LROW + z]     = make_float2(v.x, v.y);
        sl[y * LROW + z + 1] = make_float2(v.z, v.w);
    }
    __syncthreads();
    int lane = t & 127, jb = (t >> 7) * 8;
    for (int s = 6; s >= 0; --s) {
        int half = 1 << s;
        for (int j = jb; j < jb + 8; ++j) {
            int pos = j & (half - 1);
            int i0 = ((j >> s) << (s + 1)) + pos;
            float2 w = tw[pos << (6 - s)];
            float2* p0 = &sl[lane * LROW + i0];
            float2 a = p0[0], b = p0[half];
            p0[0]    = cadd(a, b);
            p0[half] = cmul(csub(a, b), w);
        }
        __syncthreads();
    }
    for (int s = 6; s >= 0; --s) {
        int half = 1 << s;
        for (int j = jb; j < jb + 8; ++j) {
            int pos = j & (half - 1);
            int i0 = ((j >> s) << (s + 1)) + pos;
            float2 w = tw[pos << (6 - s)];
            float2* p0 = &sl[i0 * LROW + lane];
            float2 a = p0[0], b = p0[half * LROW];
            p0[0]           = cadd(a, b);
            p0[half * LROW] = cmul(csub(a, b), w);
        }
        __syncthreads();
    }
    float4* dst = (float4*)(mesh + (size_t)xs * (NSZ * NSZ));
    for (int f = t; f < 8192; f += 1024) {
        int y = f >> 6, z = (f & 63) * 2;
        float2 u0 = sl[y * LROW + z], u1 = sl[y * LROW + z + 1];
        dst[f] = make_float4(u0.x, u0.y, u1.x, u1.y);
    }
}

__global__ void __launch_bounds__(1024)
fft_inv_yz(float2* __restrict__ mesh) {
    extern __shared__ float2 sl[];
    __shared__ float2 tw[64];
    int t = threadIdx.x;
    int xs = blockIdx.x;
    if (t < 64) {
        float sn, cs;
        __sincosf(6.283185307179586f * (float)t / 128.0f, &sn, &cs);
        tw[t] = make_float2(cs, -sn);
    }
    const float4* src = (const float4*)(mesh + (size_t)xs * (NSZ * NSZ));
    for (int f = t; f < 8192; f += 1024) {
        float4 v = src[f];
        int y = f >> 6, z = (f & 63) * 2;
        sl[y * LROW + z]     = make_float2(v.x, v.y);
        sl[y * LROW + z + 1] = make_float2(v.z, v.w);
    }
    __syncthreads();
    int lane = t & 127, jb = (t >> 7) * 8;
    for (int s = 0; s < 7; ++s) {
        int half = 1 << s;
        for (int j = jb; j < jb + 8; ++j) {
            int pos = j & (half - 1);
            int i0 = ((j >> s) << (s + 1)) + pos;
            float2 w = tw[pos << (6 - s)];
            float2* p0 = &sl[i0 * LROW + lane];
            float2 a = p0[0];
            float2 bw = cmulc(p0[half * LROW], w);
            p0[0]           = cadd(a, bw);
            p0[half * LROW] = csub(a, bw);
        }
        __syncthreads();
    }
    for (int s = 0; s < 7; ++s) {
        int half = 1 << s;
        for (int j = jb; j < jb + 8; ++j) {
            int pos = j & (half - 1);
            int i0 = ((j >> s) << (s + 1)) + pos;
            float2 w = tw[pos << (6 - s)];
            float2* p0 = &sl[lane * LROW + i0];
            float2 a = p0[0];
            float2 bw = cmulc(p0[half], w);
            p0[0]    = cadd(a, bw);
            p0[half] = csub(a, bw);
        }
        __syncthreads();
    }
    float4* dst = (float4*)(mesh + (size_t)xs * (NSZ * NSZ));
    for (int f = t; f < 8192; f += 1024) {
        int y = f >> 6, z = (f & 63) * 2;
        float2 u0 = sl[y * LROW + z], u1 = sl[y * LROW + z + 1];
        dst[f] = make_float4(u0.x, u0.y, u1.x, u1.y);
    }
}

__global__ void gather_plain(const float* __restrict__ pos,
                             const float* __restrict__ cell,
                             const float2* __restrict__ mesh,
                             float2* __restrict__ out, int n_atoms) {
    int a = blockIdx.x * blockDim.x + threadIdx.x;
    if (a >= n_atoms) return;
    float inv[9];
    inv3x3(cell, inv);
    int base[3];
    float w[3][4];
    stencil_pos(pos[a * 3], pos[a * 3 + 1], pos[a * 3 + 2], inv, base, w);
    float acc0 = 0.0f, acc1 = 0.0f;
#pragma unroll
    for (int l = 0; l < 4; l++) {
        int gx = (base[0] + l - 1 + NSZ) & (NSZ - 1);
#pragma unroll
        for (int m = 0; m < 4; m++) {
            int gy = (base[1] + m - 1 + NSZ) & (NSZ - 1);
            float wlm = w[0][l] * w[1][m];
            int rowb = (gx * NSZ + gy) * NSZ;
#pragma unroll
            for (int n = 0; n < 4; n++) {
                int gz = (base[2] + n - 1 + NSZ) & (NSZ - 1);
                float2 v = mesh[rowb + gz];
                float ww = wlm * w[2][n];
                acc0 += ww * v.x;
                acc1 += ww * v.y;
            }
        }
    }
    out[a] = make_float2(acc0, acc1);
}

// ---------- launch ----------

extern "C" void kernel_launch(void* const* d_in, const int* in_sizes, int n_in,
                              void* d_out, int out_size, void* d_ws, size_t ws_size,
                              hipStream_t stream) {
    const float* pos     = (const float*)d_in[0];
    const float* cell    = (const float*)d_in[1];
    const int*   species = (const int*)d_in[2];
    int n_atoms = in_sizes[0] / 3;

    // workspace layout
    char* ws = (char*)d_ws;
    float2* mesh = (float2*)ws;                                   // 16 MiB
    size_t off = (size_t)NS3 * sizeof(float2);
    int* counts = (int*)(ws + off);           off += NBUCK * 4;   // zeroed
    int* starts = (int*)(ws + off);           off += (NBUCK + 4) * 4;
    int* cursor = (int*)(ws + off);           off += NBUCK * 4;
    off = (off + 15) & ~(size_t)15;
    float4* recs     = (float4*)(ws + off);   off += (size_t)n_atoms * 16;
    int* ids         = (int*)(ws + off);      off += (size_t)n_atoms * 4;
    off = (off + 15) & ~(size_t)15;
    float2* partials = (float2*)(ws + off);   off += (size_t)n_atoms * 4 * 8;
    bool binned = (ws_size >= off);

    hipFuncSetAttribute((const void*)fft_fwd_zy_sc, hipFuncAttributeMaxDynamicSharedMemorySize, (int)LDS_BYTES);
    hipFuncSetAttribute((const void*)fft_x_g,       hipFuncAttributeMaxDynamicSharedMemorySize, (int)LDS_BYTES);
    hipFuncSetAttribute((const void*)fft_inv_yz_ga, hipFuncAttributeMaxDynamicSharedMemorySize, (int)LDS_BYTES);
    hipFuncSetAttribute((const void*)fft_fwd_zy,    hipFuncAttributeMaxDynamicSharedMemorySize, (int)LDS_BYTES);
    hipFuncSetAttribute((const void*)fft_inv_yz,    hipFuncAttributeMaxDynamicSharedMemorySize, (int)LDS_BYTES);

    int ab = (n_atoms + 255) / 256;

    if (binned) {
        hipMemsetAsync(counts, 0, NBUCK * 4, stream);
        bin_hist<<<ab, 256, 0, stream>>>(pos, cell, counts, n_atoms);
        scan4096<<<1, 1024, 0, stream>>>(counts, starts, cursor);
        bin_permute<<<ab, 256, 0, stream>>>(pos, cell, species, cursor, recs, ids, n_atoms);
        fft_fwd_zy_sc<<<NSZ, 1024, LDS_BYTES, stream>>>(recs, starts, mesh);
        fft_x_g      <<<NSZ, 1024, LDS_BYTES, stream>>>(mesh, cell, 1.0f /* SMEARING */);
        fft_inv_yz_ga<<<NSZ, 1024, LDS_BYTES, stream>>>(recs, starts, mesh, partials);
        combine<<<ab, 256, 0, stream>>>(partials, ids, (float2*)d_out, n_atoms);
    } else {
        hipMemsetAsync(mesh, 0, (size_t)NS3 * sizeof(float2), stream);
        scatter_atomic<<<ab, 256, 0, stream>>>(pos, cell, species, (float*)mesh, n_atoms);
        fft_fwd_zy<<<NSZ, 1024, LDS_BYTES, stream>>>(mesh);
        fft_x_g   <<<NSZ, 1024, LDS_BYTES, stream>>>(mesh, cell, 1.0f /* SMEARING */);
        fft_inv_yz<<<NSZ, 1024, LDS_BYTES, stream>>>(mesh);
        gather_plain<<<ab, 256, 0, stream>>>(pos, cell, mesh, (float2*)d_out, n_atoms);
    }
}